// Round 5
// baseline (77.741 us; speedup 1.0000x reference)
//
#include <hip/hip_runtime.h>

// ConjunctionLayer: out[b,j] = -1 / (-1 + sum_i log(1 - (1-x[b,i]) * W[j,i]))
// B=4096, INPUT_DIM=512, N=128, fp32.
//
// R5: occupancy via register diet. R3b had w[32]+u[32] = 128 VGPRs minimum ->
// ~2 waves/SIMD and zero headroom to pipeline x loads -> latency-bound at
// ~25% VALU duty (kernel ~22 us vs 3.8 us floor).
// Changes:
//  - drop u[]: z = 1-(1-x)w = fma(xm, wn, 1.0), wn = -w stored at load
//    (64 VGPRs), xm = 1-x computed in-loop (pk_sub; +40% floor for 2x waves).
//  - per bi, two independent products-of-32 (x live = 16 v2f at a time;
//    0.5^32 ~ 2e-10 stays normal fp32) -> one v_log_f32 per 32 elements.
//  - __launch_bounds__(512, 4): cap 128 VGPRs -> 4 waves/SIMD, 2 blocks/CU,
//    all 512 blocks resident.
// Mapping unchanged: lane<->j (64 j, half h), wave<->K-chunk (8 x 64 i),
// x loads wave-uniform (scalar-path eligible), LDS only for the K-reduction.

typedef float v2f __attribute__((ext_vector_type(2)));
typedef float v4f __attribute__((ext_vector_type(4)));

constexpr int IDIM  = 512;
constexpr int NOUT  = 128;
constexpr int BTOT  = 4096;
constexpr int KC    = 64;            // i per wave
constexpr int NB    = 16;            // b per block
constexpr int GB    = BTOT / NB;     // 256 b-groups
constexpr float LN2 = 0.69314718055994530942f;

// One product-of-32 -> one log2. xp = x[b, i0:i0+32] (wave-uniform address),
// wn = -W fragment for the same 32 i. z = fma(1-x, wn, 1) in place, then a
// 15-mul pk tree + 1 scalar mul + v_log_f32.
__device__ __forceinline__ float grouplog32(const v2f* __restrict__ xp,
                                            const v2f* __restrict__ wn) {
    v2f z[16];
    #pragma unroll
    for (int p = 0; p < 16; ++p) {
        v2f xm = 1.0f - xp[p];            // v_pk_sub (wave-uniform value)
        z[p] = xm * wn[p] + 1.0f;         // v_pk_fma: 1 - (1-x)*w
    }
    #pragma unroll
    for (int s = 8; s >= 1; s >>= 1)
        #pragma unroll
        for (int k = 0; k < s; ++k)
            z[k] = z[k] * z[k + s];       // 15 pk_mul
    return __builtin_amdgcn_logf(z[0].x * z[0].y);   // v_log_f32 (log2)
}

__global__ __launch_bounds__(512, 4)
void conj_kernel(const float* __restrict__ x,
                 const float* __restrict__ W,
                 float* __restrict__ out)
{
    __shared__ float s_p[NB * 8 * 64];   // [bi][wave][lane] partials, 32 KB

    const int tid  = threadIdx.x;
    const int lane = tid & 63;
    const int wv   = __builtin_amdgcn_readfirstlane(tid >> 6);   // 0..7, SGPR
    const int h    = blockIdx.x >> 8;        // j-half; pairs 256 apart -> same XCD
    const int bg   = blockIdx.x & (GB - 1);
    const int b0   = bg * NB;
    const int j    = h * 64 + lane;
    const int k0   = wv * KC;

    // Loop-invariant: wn = -W[j, k0:k0+64]. 32 v2f = 64 VGPRs.
    v2f wn[32];
    {
        const v4f* wp = (const v4f*)(W + (size_t)j * IDIM + k0);
        #pragma unroll
        for (int qd = 0; qd < 16; ++qd) {
            v4f t = wp[qd];
            v2f lo; lo.x = -t.x; lo.y = -t.y;
            v2f hi; hi.x = -t.z; hi.y = -t.w;
            wn[2 * qd]     = lo;
            wn[2 * qd + 1] = hi;
        }
    }

    const float* xbase = x + (size_t)b0 * IDIM + k0;   // wave-uniform

    for (int bi = 0; bi < NB; ++bi) {
        const v2f* xp = (const v2f*)(xbase + (size_t)bi * IDIM);
        float s = grouplog32(xp,      &wn[0])
                + grouplog32(xp + 16, &wn[16]);
        s_p[bi * 512 + wv * 64 + lane] = s;    // lanes consecutive: no conflict
    }
    __syncthreads();

    // Reduce the 8 K-chunks, finalize, coalesced store.
    #pragma unroll
    for (int r = 0; r < (NB * 64) / 512; ++r) {   // 2 outputs/thread
        const int idx = tid + r * 512;
        const int bi  = idx >> 6;
        const int l   = idx & 63;
        float sum = 0.0f;
        #pragma unroll
        for (int wq = 0; wq < 8; ++wq)
            sum += s_p[bi * 512 + wq * 64 + l];   // lanes consecutive: no conflict
        out[(size_t)(b0 + bi) * NOUT + h * 64 + l] = 1.0f / (1.0f - LN2 * sum);
    }
}

extern "C" void kernel_launch(void* const* d_in, const int* in_sizes, int n_in,
                              void* d_out, int out_size, void* d_ws, size_t ws_size,
                              hipStream_t stream) {
    const float* x = (const float*)d_in[0];   // (4096, 512) fp32
    const float* W = (const float*)d_in[1];   // (128, 512) fp32
    float* out = (float*)d_out;               // (4096, 128) fp32

    dim3 grid(2 * GB);                        // 512 blocks (j-half major)
    dim3 block(512);                          // 8 waves
    hipLaunchKernelGGL(conj_kernel, grid, block, 0, stream, x, W, out);
}

// Round 6
// 77.206 us; speedup vs baseline: 1.0069x; 1.0069x over previous
//
#include <hip/hip_runtime.h>

// ConjunctionLayer: out[b,j] = -1 / (-1 + sum_i log(1 - (1-x[b,i]) * W[j,i]))
// B=4096, INPUT_DIM=512, N=128, fp32.
//
// R6: R5 showed the bottleneck is occupancy-INdependent (2->4 waves/SIMD was
// neutral) -> theory: vector-L1 transaction throughput + unmerged narrow x
// loads. This round:
//  - x read as explicit float4 (global_load_dwordx4 guaranteed), one 16-float
//    chunk software-pipelined ahead (peak VGPR ~120 < 128 cap, no spill).
//  - one v_log_f32 per 64 i: product-of-64 >= 0.5^64 ~ 5e-20, normal fp32.
//  - mapping unchanged: lane<->j (64 j, half h), wave<->K-chunk (8 x 64 i),
//    wn = -W[j,k0:k0+64] resident in 64 VGPRs, z = fma(1-x, wn, 1).
//    Cross-wave K-reduction via 32 KB LDS tile; coalesced stores.

typedef float v2f __attribute__((ext_vector_type(2)));
typedef float v4f __attribute__((ext_vector_type(4)));

constexpr int IDIM  = 512;
constexpr int NOUT  = 128;
constexpr int BTOT  = 4096;
constexpr int KC    = 64;            // i per wave
constexpr int NB    = 16;            // b per block
constexpr int GB    = BTOT / NB;     // 256 b-groups
constexpr float LN2 = 0.69314718055994530942f;

__device__ __forceinline__ v2f zpair(float xx, float xy, v2f wnp) {
    v2f x2; x2.x = xx; x2.y = xy;
    v2f xm = 1.0f - x2;               // v_pk_sub (wave-uniform value)
    return xm * wnp + 1.0f;           // v_pk_fma: 1 - (1-x)*w
}

// 16-i chunk -> partial product (v2f). 8 sub + 8 fma + 7 mul, all packed.
__device__ __forceinline__ v2f chunkprod(float4 a0, float4 a1, float4 a2, float4 a3,
                                         const v2f* __restrict__ wn) {
    v2f z0 = zpair(a0.x, a0.y, wn[0]);
    v2f z1 = zpair(a0.z, a0.w, wn[1]);
    v2f z2 = zpair(a1.x, a1.y, wn[2]);
    v2f z3 = zpair(a1.z, a1.w, wn[3]);
    v2f z4 = zpair(a2.x, a2.y, wn[4]);
    v2f z5 = zpair(a2.z, a2.w, wn[5]);
    v2f z6 = zpair(a3.x, a3.y, wn[6]);
    v2f z7 = zpair(a3.z, a3.w, wn[7]);
    v2f q0 = z0 * z1, q1 = z2 * z3, q2 = z4 * z5, q3 = z6 * z7;
    return (q0 * q1) * (q2 * q3);
}

__global__ __launch_bounds__(512, 4)
void conj_kernel(const float* __restrict__ x,
                 const float* __restrict__ W,
                 float* __restrict__ out)
{
    __shared__ float s_p[NB * 8 * 64];   // [bi][wave][lane] partials, 32 KB

    const int tid  = threadIdx.x;
    const int lane = tid & 63;
    const int wv   = __builtin_amdgcn_readfirstlane(tid >> 6);   // 0..7, SGPR
    const int h    = blockIdx.x >> 8;        // j-half; pairs 256 apart -> same XCD
    const int bg   = blockIdx.x & (GB - 1);
    const int b0   = bg * NB;
    const int j    = h * 64 + lane;
    const int k0   = wv * KC;

    // Loop-invariant: wn = -W[j, k0:k0+64]. 32 v2f = 64 VGPRs. (Per-lane
    // row-strided load, one-time.)
    v2f wn[32];
    {
        const v4f* wp = (const v4f*)(W + (size_t)j * IDIM + k0);
        #pragma unroll
        for (int qd = 0; qd < 16; ++qd) {
            v4f t = wp[qd];
            v2f lo; lo.x = -t.x; lo.y = -t.y;
            v2f hi; hi.x = -t.z; hi.y = -t.w;
            wn[2 * qd]     = lo;
            wn[2 * qd + 1] = hi;
        }
    }

    // x stream: wave-uniform addresses, float4 granularity.
    // idx(bi, c, q) = bi*128 + c*4 + q   (row stride 512 floats = 128 float4)
    const float4* xq = (const float4*)(x + (size_t)b0 * IDIM + k0);

    // Prime the pipeline with chunk (bi=0, c=0).
    float4 xa0 = xq[0], xa1 = xq[1], xa2 = xq[2], xa3 = xq[3];

    for (int bi = 0; bi < NB; ++bi) {
        v2f pc[4];
        #pragma unroll
        for (int c = 0; c < 4; ++c) {
            // Prefetch next chunk (clamped reload on the very last chunk).
            int nbi = (c == 3) ? bi + 1 : bi;
            int nc  = (c == 3) ? 0 : c + 1;
            if (nbi == NB) { nbi = NB - 1; nc = 3; }
            const int ni = nbi * 128 + nc * 4;
            float4 xb0 = xq[ni + 0], xb1 = xq[ni + 1];
            float4 xb2 = xq[ni + 2], xb3 = xq[ni + 3];

            pc[c] = chunkprod(xa0, xa1, xa2, xa3, &wn[c * 8]);

            xa0 = xb0; xa1 = xb1; xa2 = xb2; xa3 = xb3;
        }
        v2f m = (pc[0] * pc[1]) * (pc[2] * pc[3]);
        // product of all 64 z's in (0.5^64, 1] -> one log2
        s_p[bi * 512 + wv * 64 + lane] = __builtin_amdgcn_logf(m.x * m.y);
    }
    __syncthreads();

    // Reduce the 8 K-chunks, finalize, coalesced store.
    #pragma unroll
    for (int r = 0; r < (NB * 64) / 512; ++r) {   // 2 outputs/thread
        const int idx = tid + r * 512;
        const int bi  = idx >> 6;
        const int l   = idx & 63;
        float sum = 0.0f;
        #pragma unroll
        for (int wq = 0; wq < 8; ++wq)
            sum += s_p[bi * 512 + wq * 64 + l];   // lanes consecutive: no conflict
        out[(size_t)(b0 + bi) * NOUT + h * 64 + l] = 1.0f / (1.0f - LN2 * sum);
    }
}

extern "C" void kernel_launch(void* const* d_in, const int* in_sizes, int n_in,
                              void* d_out, int out_size, void* d_ws, size_t ws_size,
                              hipStream_t stream) {
    const float* x = (const float*)d_in[0];   // (4096, 512) fp32
    const float* W = (const float*)d_in[1];   // (128, 512) fp32
    float* out = (float*)d_out;               // (4096, 128) fp32

    dim3 grid(2 * GB);                        // 512 blocks (j-half major)
    dim3 block(512);                          // 8 waves
    hipLaunchKernelGGL(conj_kernel, grid, block, 0, stream, x, W, out);
}